// Round 1
// baseline (313.308 us; speedup 1.0000x reference)
//
#include <hip/hip_runtime.h>
#include <hip/hip_bf16.h>

// NeuroselectiveLinear: y = gather(x, in_idx) @ W^T + b, scattered into a
// zeroed [B,S,4096] buffer. Strategy: bf16 MFMA GEMM over active dims,
// dense (zero-merged) output row writes via inverse pos[] map.

typedef unsigned short u16;
typedef u16   u16x4 __attribute__((ext_vector_type(4)));
typedef u16   u16x8 __attribute__((ext_vector_type(8)));
typedef int   i32x4 __attribute__((ext_vector_type(4)));
typedef float f32x4 __attribute__((ext_vector_type(4)));
typedef __bf16 bf16x8 __attribute__((ext_vector_type(8)));

constexpr int IN_F  = 4096;
constexpr int OUT_F = 4096;
constexpr int AI    = 1024;   // ACTIVE_IN  (K)
constexpr int AO    = 1024;   // ACTIVE_OUT (N)
constexpr int M_ROWS = 4 * 2048; // 8192
constexpr int BM = 32;        // rows per block
constexpr int BK = 64;        // K per LDS stage
constexpr int NTHREADS = 512; // 8 waves

__device__ __forceinline__ u16 f2bf(float f) {
    union { __hip_bfloat16 h; u16 u; } cv;
    cv.h = __float2bfloat16(f);   // RNE
    return cv.u;
}

// pos[out_idx[j]] = j  (pos pre-memset to -1 via hipMemsetAsync 0xFF)
// Wb = bf16(W), row-major [AO][AI]
__global__ void prep_kernel(const float* __restrict__ W,
                            const int* __restrict__ out_idx,
                            u16* __restrict__ Wb, int* __restrict__ pos) {
    int t = blockIdx.x * blockDim.x + threadIdx.x; // 0..262143
    if (t < AO) pos[out_idx[t]] = t;
    f32x4 w = reinterpret_cast<const f32x4*>(W)[t];
    u16x4 v;
    v.x = f2bf(w.x); v.y = f2bf(w.y); v.z = f2bf(w.z); v.w = f2bf(w.w);
    reinterpret_cast<u16x4*>(Wb)[t] = v;
}

// Xa[m][k] = bf16(x[m][in_idx[k]])   (compact gathered activations)
__global__ void gather_kernel(const float* __restrict__ x,
                              const int* __restrict__ in_idx,
                              u16* __restrict__ Xa) {
    int t = blockIdx.x * blockDim.x + threadIdx.x; // 0..1048575
    int m  = t >> 7;
    int kc = (t & 127) * 8;
    const float* xr = x + (size_t)m * IN_F;
    u16x8 v;
#pragma unroll
    for (int j = 0; j < 8; ++j) v[j] = f2bf(xr[in_idx[kc + j]]);
    *reinterpret_cast<u16x8*>(Xa + (size_t)m * AI + kc) = v;
}

// Each block: 32 rows x all 1024 active outputs, then dense 32x4096 write.
// 8 waves, wave w owns n in [w*128, w*128+128): 2 m-frags x 8 n-frags of
// 16x16x32 bf16 MFMA. B-fragments read directly from L2-resident Wb.
template <bool PRE>
__global__ __launch_bounds__(NTHREADS, 1)
void gemm_kernel(const float* __restrict__ x,
                 const u16* __restrict__ Xa,
                 const u16* __restrict__ Wb,
                 const float* __restrict__ bias,
                 const int* __restrict__ in_idx,
                 const int* __restrict__ pos,
                 float* __restrict__ out) {
    __shared__ u16 As[2][BM][BK + 8];      // +16B pad: 2-way-max LDS banks, 16B-aligned rows
    __shared__ float ys[BM][AO + 1];       // +1 pad: conflict-free epilogue writes

    const int tid  = threadIdx.x;
    const int wid  = tid >> 6;
    const int lane = tid & 63;
    const int n_lo = lane & 15;
    const int kg   = lane >> 4;            // k-group 0..3
    const int m_base = blockIdx.x * BM;

    float bv[8];
#pragma unroll
    for (int f = 0; f < 8; ++f) bv[f] = bias[wid * 128 + f * 16 + n_lo];

    f32x4 acc[2][8];
#pragma unroll
    for (int mf = 0; mf < 2; ++mf)
#pragma unroll
        for (int f = 0; f < 8; ++f) acc[mf][f] = (f32x4)0.0f;

    // A staging: 512 threads x 8B = 32x64 bf16 tile
    const int srow = tid >> 4;           // 0..31
    const int sc4  = (tid & 15) * 4;     // ushort4 col

    auto stage = [&](int buf, int k0) {
        if constexpr (PRE) {
            const u16* src = Xa + (size_t)(m_base + srow) * AI + k0 + sc4;
            *reinterpret_cast<u16x4*>(&As[buf][srow][sc4]) =
                *reinterpret_cast<const u16x4*>(src);
        } else {
            const float* xr = x + (size_t)(m_base + srow) * IN_F;
            u16x4 v;
#pragma unroll
            for (int j = 0; j < 4; ++j) v[j] = f2bf(xr[in_idx[k0 + sc4 + j]]);
            *reinterpret_cast<u16x4*>(&As[buf][srow][sc4]) = v;
        }
    };

    stage(0, 0);
    int buf = 0;
    for (int kt = 0; kt < AI / BK; ++kt) {
        __syncthreads();
        if (kt + 1 < AI / BK) stage(buf ^ 1, (kt + 1) * BK);
        const int k0 = kt * BK;
#pragma unroll
        for (int kk = 0; kk < BK; kk += 32) {
            bf16x8 a[2];
            a[0] = *reinterpret_cast<const bf16x8*>(&As[buf][n_lo][kk + kg * 8]);
            a[1] = *reinterpret_cast<const bf16x8*>(&As[buf][16 + n_lo][kk + kg * 8]);
#pragma unroll
            for (int f = 0; f < 8; ++f) {
                const int n = wid * 128 + f * 16 + n_lo;
                bf16x8 bfr = *reinterpret_cast<const bf16x8*>(
                    Wb + (size_t)n * AI + k0 + kk + kg * 8);
                acc[0][f] = __builtin_amdgcn_mfma_f32_16x16x32_bf16(a[0], bfr, acc[0][f], 0, 0, 0);
                acc[1][f] = __builtin_amdgcn_mfma_f32_16x16x32_bf16(a[1], bfr, acc[1][f], 0, 0, 0);
            }
        }
        buf ^= 1;
    }

    __syncthreads();
    // park y tile (+bias) in LDS: ys[m][j] for active j
#pragma unroll
    for (int mf = 0; mf < 2; ++mf)
#pragma unroll
        for (int f = 0; f < 8; ++f)
#pragma unroll
            for (int r = 0; r < 4; ++r)
                ys[mf * 16 + kg * 4 + r][wid * 128 + f * 16 + n_lo] =
                    acc[mf][f][r] + bv[f];
    __syncthreads();

    // dense write: every out element of these 32 rows written exactly once
    for (int i = tid; i < BM * (OUT_F / 4); i += NTHREADS) {
        int m  = i >> 10;        // OUT_F/4 = 1024
        int o4 = i & 1023;
        i32x4 p = reinterpret_cast<const i32x4*>(pos)[o4];
        f32x4 v;
        v.x = (p.x >= 0) ? ys[m][p.x] : 0.0f;
        v.y = (p.y >= 0) ? ys[m][p.y] : 0.0f;
        v.z = (p.z >= 0) ? ys[m][p.z] : 0.0f;
        v.w = (p.w >= 0) ? ys[m][p.w] : 0.0f;
        reinterpret_cast<f32x4*>(out + (size_t)(m_base + m) * OUT_F)[o4] = v;
    }
}

extern "C" void kernel_launch(void* const* d_in, const int* in_sizes, int n_in,
                              void* d_out, int out_size, void* d_ws, size_t ws_size,
                              hipStream_t stream) {
    const float* x      = (const float*)d_in[0];
    const float* W      = (const float*)d_in[1];
    const float* b      = (const float*)d_in[2];
    const int*   in_idx = (const int*)d_in[3];
    const int*   out_idx= (const int*)d_in[4];
    float* out = (float*)d_out;

    char* ws = (char*)d_ws;
    int* pos = (int*)ws;                                   // 16 KB
    u16* Wb  = (u16*)(ws + 16384);                         // 2 MB
    u16* Xa  = (u16*)(ws + 16384 + 2 * 1024 * 1024);       // 16 MB
    const size_t NEED_FULL = 16384 + 2u * 1024 * 1024 + (size_t)M_ROWS * AI * 2;

    hipMemsetAsync(pos, 0xFF, OUT_F * sizeof(int), stream); // pos = -1
    prep_kernel<<<1024, 256, 0, stream>>>(W, out_idx, Wb, pos);

    if (ws_size >= NEED_FULL) {
        gather_kernel<<<(M_ROWS * AI / 8) / 256, 256, 0, stream>>>(x, in_idx, Xa);
        gemm_kernel<true><<<M_ROWS / BM, NTHREADS, 0, stream>>>(x, Xa, Wb, b, in_idx, pos, out);
    } else {
        gemm_kernel<false><<<M_ROWS / BM, NTHREADS, 0, stream>>>(x, Xa, Wb, b, in_idx, pos, out);
    }
}

// Round 2
// 281.599 us; speedup vs baseline: 1.1126x; 1.1126x over previous
//
#include <hip/hip_runtime.h>
#include <hip/hip_bf16.h>

// NeuroselectiveLinear: y = gather(x, in_idx) @ W^T + b scattered into a
// zeroed [B,S,4096] buffer.
// Pipeline: prep (bf16 W + inverse pos map) -> gather (coalesced x -> compact
// bf16 Xa) -> gemm128 (m97-style MFMA, writes compact Y into out[:, :1024])
// -> expand (per-row in-place dense write with zero merge).

typedef unsigned short u16;
typedef u16   u16x4 __attribute__((ext_vector_type(4)));
typedef int   i32x4 __attribute__((ext_vector_type(4)));
typedef float f32x4 __attribute__((ext_vector_type(4)));
typedef __bf16 bf16x8 __attribute__((ext_vector_type(8)));

constexpr int IN_F  = 4096;
constexpr int OUT_F = 4096;
constexpr int AI    = 1024;      // ACTIVE_IN  (K)
constexpr int AO    = 1024;      // ACTIVE_OUT (N)
constexpr int M_ROWS = 4 * 2048; // 8192
constexpr int NT_K  = AI / 64;   // 16 K-steps

__device__ __forceinline__ u16 f2bf(float f) {
    union { __hip_bfloat16 h; u16 u; } cv;
    cv.h = __float2bfloat16(f);   // RNE
    return cv.u;
}

// pos[out_idx[j]] = j  (pos pre-memset to -1 via hipMemsetAsync 0xFF)
// Wb = bf16(W), row-major [AO][AI]
__global__ void prep_kernel(const float* __restrict__ W,
                            const int* __restrict__ out_idx,
                            u16* __restrict__ Wb, int* __restrict__ pos) {
    int t = blockIdx.x * blockDim.x + threadIdx.x; // 0..262143
    if (t < AO) pos[out_idx[t]] = t;
    f32x4 w = reinterpret_cast<const f32x4*>(W)[t];
    u16x4 v;
    v.x = f2bf(w.x); v.y = f2bf(w.y); v.z = f2bf(w.z); v.w = f2bf(w.w);
    reinterpret_cast<u16x4*>(Wb)[t] = v;
}

// One block per row: coalesced dense row load -> LDS, then LDS gather.
__global__ __launch_bounds__(256)
void gather_kernel(const float* __restrict__ x,
                   const int* __restrict__ in_idx,
                   u16* __restrict__ Xa) {
    __shared__ float xrow[IN_F];
    const int m = blockIdx.x;
    const int t = threadIdx.x;
    const f32x4* src = reinterpret_cast<const f32x4*>(x + (size_t)m * IN_F);
#pragma unroll
    for (int i = 0; i < 4; ++i)
        *reinterpret_cast<f32x4*>(&xrow[i * 1024 + t * 4]) = src[i * 256 + t];
    __syncthreads();
    i32x4 idx = reinterpret_cast<const i32x4*>(in_idx)[t];
    u16x4 v;
    v.x = f2bf(xrow[idx.x]);
    v.y = f2bf(xrow[idx.y]);
    v.z = f2bf(xrow[idx.z]);
    v.w = f2bf(xrow[idx.w]);
    reinterpret_cast<u16x4*>(Xa + (size_t)m * AI)[t] = v;
}

// 128x128 tile, BK=64, 4 waves (2x2), 4x4 16x16x32 frags per wave.
// Writes compact Y (+bias) into out[m][0:1024] (expanded in-place later).
template <bool PRE>
__global__ __launch_bounds__(256, 2)
void gemm128(const float* __restrict__ x, const u16* __restrict__ Xa,
             const u16* __restrict__ Wb, const float* __restrict__ bias,
             const int* __restrict__ in_idx, float* __restrict__ out) {
    __shared__ u16 As[2][128 * 64];
    __shared__ u16 Bs[2][128 * 64];
    const int tid  = threadIdx.x;
    const int wid  = tid >> 6;
    const int lane = tid & 63;
    const int n_lo = lane & 15;
    const int kg   = lane >> 4;
    // XCD-aware swizzle: 512 blocks, each XCD gets 64 contiguous tiles
    // (8 mb-groups x all nb) -> A panel (2MB) + B (2MB) fit its 4MB L2.
    const int orig = blockIdx.x;
    const int wgid = (orig & 7) * 64 + (orig >> 3);
    const int mb = wgid >> 3, nb = wgid & 7;
    const int m0 = mb * 128, n0 = nb * 128;
    const int wm = wid >> 1, wn = wid & 1;

    auto stage = [&](int buf, int k0) {
        if constexpr (PRE) {
            const int r8 = lane >> 3;
            const int c8 = (lane & 7) * 8;
#pragma unroll
            for (int c = 0; c < 4; ++c) {
                const int row = wid * 32 + c * 8;
                __builtin_amdgcn_global_load_lds(
                    (const __attribute__((address_space(1))) void*)
                        (Xa + (size_t)(m0 + row + r8) * AI + k0 + c8),
                    (__attribute__((address_space(3))) void*)&As[buf][row * 64],
                    16, 0, 0);
                __builtin_amdgcn_global_load_lds(
                    (const __attribute__((address_space(1))) void*)
                        (Wb + (size_t)(n0 + row + r8) * AI + k0 + c8),
                    (__attribute__((address_space(3))) void*)&Bs[buf][row * 64],
                    16, 0, 0);
            }
        } else {
            const int rr = tid >> 1;          // 0..127
            const int cc = (tid & 1) * 32;    // two 32-col halves
#pragma unroll
            for (int j4 = 0; j4 < 32; j4 += 4) {
                u16x4 va;
#pragma unroll
                for (int j = 0; j < 4; ++j)
                    va[j] = f2bf(x[(size_t)(m0 + rr) * IN_F + in_idx[k0 + cc + j4 + j]]);
                *reinterpret_cast<u16x4*>(&As[buf][rr * 64 + cc + j4]) = va;
                *reinterpret_cast<u16x4*>(&Bs[buf][rr * 64 + cc + j4]) =
                    *reinterpret_cast<const u16x4*>(Wb + (size_t)(n0 + rr) * AI + k0 + cc + j4);
            }
        }
    };

    f32x4 acc[4][4];
#pragma unroll
    for (int i = 0; i < 4; ++i)
#pragma unroll
        for (int j = 0; j < 4; ++j) acc[i][j] = (f32x4)0.0f;

    stage(0, 0);
    int buf = 0;
    for (int kt = 0; kt < NT_K; ++kt) {
        __syncthreads();
        if (kt + 1 < NT_K) stage(buf ^ 1, (kt + 1) * 64);
#pragma unroll
        for (int kk = 0; kk < 64; kk += 32) {
            bf16x8 a[4], b[4];
#pragma unroll
            for (int i = 0; i < 4; ++i)
                a[i] = *reinterpret_cast<const bf16x8*>(
                    &As[buf][(wm * 64 + i * 16 + n_lo) * 64 + kk + kg * 8]);
#pragma unroll
            for (int j = 0; j < 4; ++j)
                b[j] = *reinterpret_cast<const bf16x8*>(
                    &Bs[buf][(wn * 64 + j * 16 + n_lo) * 64 + kk + kg * 8]);
#pragma unroll
            for (int i = 0; i < 4; ++i)
#pragma unroll
                for (int j = 0; j < 4; ++j)
                    acc[i][j] = __builtin_amdgcn_mfma_f32_16x16x32_bf16(
                        a[i], b[j], acc[i][j], 0, 0, 0);
        }
        buf ^= 1;
    }

    float bv[4];
#pragma unroll
    for (int j = 0; j < 4; ++j) bv[j] = bias[n0 + wn * 64 + j * 16 + n_lo];
#pragma unroll
    for (int i = 0; i < 4; ++i) {
        const int gm = m0 + wm * 64 + i * 16 + kg * 4;
#pragma unroll
        for (int j = 0; j < 4; ++j) {
            const int gn = n0 + wn * 64 + j * 16 + n_lo;
#pragma unroll
            for (int r = 0; r < 4; ++r)
                out[(size_t)(gm + r) * OUT_F + gn] = acc[i][j][r] + bv[j];
        }
    }
}

// One block per row: load compact Y (out[m][0:1024]) to LDS, then write the
// dense 4096-wide row with zeros merged via pos[]. Row-private => in-place OK.
__global__ __launch_bounds__(256)
void expand_kernel(const int* __restrict__ pos, float* __restrict__ out) {
    __shared__ float yrow[AO];
    const int m = blockIdx.x;
    const int t = threadIdx.x;
    float* row = out + (size_t)m * OUT_F;
    *reinterpret_cast<f32x4*>(&yrow[t * 4]) =
        *reinterpret_cast<const f32x4*>(row + t * 4);
    __syncthreads();
    const i32x4* pos4 = reinterpret_cast<const i32x4*>(pos);
#pragma unroll
    for (int c = 0; c < 4; ++c) {
        const int o4 = c * 256 + t;
        i32x4 p = pos4[o4];
        f32x4 v;
        v.x = (p.x >= 0) ? yrow[p.x] : 0.0f;
        v.y = (p.y >= 0) ? yrow[p.y] : 0.0f;
        v.z = (p.z >= 0) ? yrow[p.z] : 0.0f;
        v.w = (p.w >= 0) ? yrow[p.w] : 0.0f;
        *reinterpret_cast<f32x4*>(row + o4 * 4) = v;
    }
}

extern "C" void kernel_launch(void* const* d_in, const int* in_sizes, int n_in,
                              void* d_out, int out_size, void* d_ws, size_t ws_size,
                              hipStream_t stream) {
    const float* x      = (const float*)d_in[0];
    const float* W      = (const float*)d_in[1];
    const float* b      = (const float*)d_in[2];
    const int*   in_idx = (const int*)d_in[3];
    const int*   out_idx= (const int*)d_in[4];
    float* out = (float*)d_out;

    char* ws = (char*)d_ws;
    int* pos = (int*)ws;                                   // 16 KB
    u16* Wb  = (u16*)(ws + 16384);                         // 2 MB
    u16* Xa  = (u16*)(ws + 16384 + 2 * 1024 * 1024);       // 16 MB
    const size_t NEED_FULL = 16384 + 2u * 1024 * 1024 + (size_t)M_ROWS * AI * 2;

    hipMemsetAsync(pos, 0xFF, OUT_F * sizeof(int), stream); // pos = -1
    prep_kernel<<<1024, 256, 0, stream>>>(W, out_idx, Wb, pos);

    if (ws_size >= NEED_FULL) {
        gather_kernel<<<M_ROWS, 256, 0, stream>>>(x, in_idx, Xa);
        gemm128<true><<<(M_ROWS / 128) * (AO / 128), 256, 0, stream>>>(
            x, Xa, Wb, b, in_idx, out);
    } else {
        gemm128<false><<<(M_ROWS / 128) * (AO / 128), 256, 0, stream>>>(
            x, Xa, Wb, b, in_idx, out);
    }
    expand_kernel<<<M_ROWS, 256, 0, stream>>>(pos, out);
}